// Round 5
// baseline (134.519 us; speedup 1.0000x reference)
//
#include <hip/hip_runtime.h>

#define NUM_FEATURES 256
#define NUM_SAMPLES  262144
#define BATCH        1024

typedef float f4 __attribute__((ext_vector_type(4)));

#define COPY_BLOCKS 2048
#define COPY_THREADS 256
#define UNROLL 8

// Streaming table copy: 256 MiB read + 256 MiB write.
// 8 independent 16B loads in flight per thread before the stores drain them;
// n4 = 32 * (COPY_BLOCKS*COPY_THREADS) exactly -> no tail, full coalescing.
__global__ __launch_bounds__(COPY_THREADS) void table_copy(
    const f4* __restrict__ src, f4* __restrict__ dst, long n4)
{
    const long tid = (long)blockIdx.x * COPY_THREADS + threadIdx.x;
    const long T = (long)COPY_BLOCKS * COPY_THREADS;  // 524288 threads
    for (long base = tid; base < n4; base += UNROLL * T) {
        f4 v[UNROLL];
        #pragma unroll
        for (int u = 0; u < UNROLL; ++u)
            v[u] = __builtin_nontemporal_load(&src[base + u * T]);
        #pragma unroll
        for (int u = 0; u < UNROLL; ++u)
            __builtin_nontemporal_store(v[u], &dst[base + u * T]);
    }
}

// One wave per batch entry. Block b owns target y = targets[b] iff b is the
// FIRST occurrence of y. Targets are staged in LDS so ownership check and
// chain scan are ballot-based (<=16 iterations), not serial global loads.
__global__ __launch_bounds__(64) void memory_bank_update(
    const float* __restrict__ inputs,    // [BATCH, F]
    const int*   __restrict__ targets,   // [BATCH]
    const float* __restrict__ features,  // [NUM_SAMPLES, F] (original table)
    float*       __restrict__ out)       // [NUM_SAMPLES, F] (already copied)
{
    __shared__ int t[BATCH];
    const int lane = threadIdx.x;  // 0..63
    const int b = blockIdx.x;

    // Stage all 1024 targets: 4 rounds of coalesced int4 loads.
    const int4* tg4 = reinterpret_cast<const int4*>(targets);
    int4* t4 = reinterpret_cast<int4*>(t);
    #pragma unroll
    for (int k = 0; k < BATCH / 4 / 64; ++k)
        t4[k * 64 + lane] = tg4[k * 64 + lane];
    __syncthreads();

    const int y = t[b];

    // Ownership: does y appear in t[0..b-1]?  Ballot over 64-wide chunks.
    for (int base = 0; base < b; base += 64) {
        const int j = base + lane;
        if (__any(j < b && t[j] == y)) return;  // earlier occurrence owns it
    }

    f4 v = reinterpret_cast<const f4*>(features + (size_t)y * NUM_FEATURES)[lane];

    const float m  = 0.1f;
    const float om = 1.0f - m;

    // Chain scan: find all i in [b, BATCH) with t[i]==y, in order, via
    // ballot + ffs. Mask is wave-uniform -> non-divergent processing loop.
    for (int base = b & ~63; base < BATCH; base += 64) {
        const int i = base + lane;
        unsigned long long mask = __ballot(i >= b && t[i] == y);
        while (mask) {
            const int i0 = base + (__ffsll((long long)mask) - 1);
            mask &= mask - 1;

            f4 x = reinterpret_cast<const f4*>(
                       inputs + (size_t)i0 * NUM_FEATURES)[lane];
            v.x = m * v.x + om * x.x;
            v.y = m * v.y + om * x.y;
            v.z = m * v.z + om * x.z;
            v.w = m * v.w + om * x.w;

            float s = v.x * v.x + v.y * v.y + v.z * v.z + v.w * v.w;
            #pragma unroll
            for (int off = 32; off > 0; off >>= 1)
                s += __shfl_xor(s, off);

            const float inv = 1.0f / fmaxf(sqrtf(s), 1e-12f);
            v.x *= inv; v.y *= inv; v.z *= inv; v.w *= inv;
        }
    }

    reinterpret_cast<f4*>(out + (size_t)y * NUM_FEATURES)[lane] = v;
}

extern "C" void kernel_launch(void* const* d_in, const int* in_sizes, int n_in,
                              void* d_out, int out_size, void* d_ws, size_t ws_size,
                              hipStream_t stream) {
    const float* inputs   = (const float*)d_in[0];
    const int*   targets  = (const int*)d_in[1];
    const float* features = (const float*)d_in[2];
    float*       out      = (float*)d_out;

    const long n4 = (long)NUM_SAMPLES * NUM_FEATURES / 4;  // 16.7M float4
    table_copy<<<COPY_BLOCKS, COPY_THREADS, 0, stream>>>(
        reinterpret_cast<const f4*>(features),
        reinterpret_cast<f4*>(out), n4);

    // Then overwrite the 1024 touched rows with the chained updates.
    memory_bank_update<<<BATCH, 64, 0, stream>>>(inputs, targets, features, out);
}

// Round 6
// 103.090 us; speedup vs baseline: 1.3049x; 1.3049x over previous
//
#include <hip/hip_runtime.h>

#define NUM_FEATURES 256
#define NUM_SAMPLES  262144
#define BATCH        1024

typedef float f4 __attribute__((ext_vector_type(4)));

#define COPY_BLOCKS 2048
#define COPY_THREADS 256

// Streaming table copy: 256 MiB read + 256 MiB write, 16 B/lane coalesced.
// Loads nontemporal (no L2 allocation for the one-shot read stream);
// stores PLAIN so they use the L2 write-back path (fill kernel sustains
// 7 TB/s through it). Simple grid-stride: R5's 8-way batch regressed.
__global__ __launch_bounds__(COPY_THREADS) void table_copy(
    const f4* __restrict__ src, f4* __restrict__ dst, long n4)
{
    long i = (long)blockIdx.x * COPY_THREADS + threadIdx.x;
    const long stride = (long)COPY_BLOCKS * COPY_THREADS;
    for (; i < n4; i += stride) {
        f4 v = __builtin_nontemporal_load(&src[i]);
        dst[i] = v;
    }
}

// One wave per batch entry. Block b owns target y = targets[b] iff b is the
// FIRST occurrence of y. Targets are staged in LDS so ownership check and
// chain scan are ballot-based (<=16 iterations), not serial global loads.
__global__ __launch_bounds__(64) void memory_bank_update(
    const float* __restrict__ inputs,    // [BATCH, F]
    const int*   __restrict__ targets,   // [BATCH]
    const float* __restrict__ features,  // [NUM_SAMPLES, F] (original table)
    float*       __restrict__ out)       // [NUM_SAMPLES, F] (already copied)
{
    __shared__ int t[BATCH];
    const int lane = threadIdx.x;  // 0..63
    const int b = blockIdx.x;

    // Stage all 1024 targets: 4 rounds of coalesced int4 loads.
    const int4* tg4 = reinterpret_cast<const int4*>(targets);
    int4* t4 = reinterpret_cast<int4*>(t);
    #pragma unroll
    for (int k = 0; k < BATCH / 4 / 64; ++k)
        t4[k * 64 + lane] = tg4[k * 64 + lane];
    __syncthreads();

    const int y = t[b];

    // Ownership: does y appear in t[0..b-1]?  Ballot over 64-wide chunks.
    for (int base = 0; base < b; base += 64) {
        const int j = base + lane;
        if (__any(j < b && t[j] == y)) return;  // earlier occurrence owns it
    }

    f4 v = reinterpret_cast<const f4*>(features + (size_t)y * NUM_FEATURES)[lane];

    const float m  = 0.1f;
    const float om = 1.0f - m;

    // Chain scan: find all i in [b, BATCH) with t[i]==y, in order, via
    // ballot + ffs. Mask is wave-uniform -> non-divergent processing loop.
    for (int base = b & ~63; base < BATCH; base += 64) {
        const int i = base + lane;
        unsigned long long mask = __ballot(i >= b && t[i] == y);
        while (mask) {
            const int i0 = base + (__ffsll((long long)mask) - 1);
            mask &= mask - 1;

            f4 x = reinterpret_cast<const f4*>(
                       inputs + (size_t)i0 * NUM_FEATURES)[lane];
            v.x = m * v.x + om * x.x;
            v.y = m * v.y + om * x.y;
            v.z = m * v.z + om * x.z;
            v.w = m * v.w + om * x.w;

            float s = v.x * v.x + v.y * v.y + v.z * v.z + v.w * v.w;
            #pragma unroll
            for (int off = 32; off > 0; off >>= 1)
                s += __shfl_xor(s, off);

            const float inv = 1.0f / fmaxf(sqrtf(s), 1e-12f);
            v.x *= inv; v.y *= inv; v.z *= inv; v.w *= inv;
        }
    }

    reinterpret_cast<f4*>(out + (size_t)y * NUM_FEATURES)[lane] = v;
}

extern "C" void kernel_launch(void* const* d_in, const int* in_sizes, int n_in,
                              void* d_out, int out_size, void* d_ws, size_t ws_size,
                              hipStream_t stream) {
    const float* inputs   = (const float*)d_in[0];
    const int*   targets  = (const int*)d_in[1];
    const float* features = (const float*)d_in[2];
    float*       out      = (float*)d_out;

    const long n4 = (long)NUM_SAMPLES * NUM_FEATURES / 4;  // 16.7M float4
    table_copy<<<COPY_BLOCKS, COPY_THREADS, 0, stream>>>(
        reinterpret_cast<const f4*>(features),
        reinterpret_cast<f4*>(out), n4);

    // Then overwrite the 1024 touched rows with the chained updates.
    memory_bank_update<<<BATCH, 64, 0, stream>>>(inputs, targets, features, out);
}

// Round 7
// 96.131 us; speedup vs baseline: 1.3993x; 1.0724x over previous
//
#include <hip/hip_runtime.h>

#define NUM_FEATURES 256
#define NUM_SAMPLES  262144
#define BATCH        1024

typedef float f4 __attribute__((ext_vector_type(4)));

#define COPY_BLOCKS 2048
#define COPY_THREADS 256

// Streaming table copy: 256 MiB read + 256 MiB write, 16 B/lane coalesced.
// 2-deep pipelined: two independent loads in flight before either store's
// vmcnt wait. Streams are T*16B = 8 MiB apart (R5's 8-way/64MiB footprint
// thrashed DRAM row buffers; 2-way/16MiB should not).
// n4 = 32*T exactly -> no tail guards.
__global__ __launch_bounds__(COPY_THREADS) void table_copy(
    const f4* __restrict__ src, f4* __restrict__ dst, long n4)
{
    const long tid = (long)blockIdx.x * COPY_THREADS + threadIdx.x;
    const long T = (long)COPY_BLOCKS * COPY_THREADS;  // 524288
    for (long i = tid; i < n4; i += 2 * T) {
        f4 v0 = __builtin_nontemporal_load(&src[i]);
        f4 v1 = __builtin_nontemporal_load(&src[i + T]);
        dst[i] = v0;
        dst[i + T] = v1;
    }
}

// One wave per batch entry. Block b owns target y = targets[b] iff b is the
// FIRST occurrence of y. Targets are staged in LDS so ownership check and
// chain scan are ballot-based (<=16 iterations), not serial global loads.
__global__ __launch_bounds__(64) void memory_bank_update(
    const float* __restrict__ inputs,    // [BATCH, F]
    const int*   __restrict__ targets,   // [BATCH]
    const float* __restrict__ features,  // [NUM_SAMPLES, F] (original table)
    float*       __restrict__ out)       // [NUM_SAMPLES, F] (already copied)
{
    __shared__ int t[BATCH];
    const int lane = threadIdx.x;  // 0..63
    const int b = blockIdx.x;

    // Stage all 1024 targets: 4 rounds of coalesced int4 loads.
    const int4* tg4 = reinterpret_cast<const int4*>(targets);
    int4* t4 = reinterpret_cast<int4*>(t);
    #pragma unroll
    for (int k = 0; k < BATCH / 4 / 64; ++k)
        t4[k * 64 + lane] = tg4[k * 64 + lane];
    __syncthreads();

    const int y = t[b];

    // Ownership: does y appear in t[0..b-1]?  Ballot over 64-wide chunks.
    for (int base = 0; base < b; base += 64) {
        const int j = base + lane;
        if (__any(j < b && t[j] == y)) return;  // earlier occurrence owns it
    }

    f4 v = reinterpret_cast<const f4*>(features + (size_t)y * NUM_FEATURES)[lane];

    const float m  = 0.1f;
    const float om = 1.0f - m;

    // Chain scan: find all i in [b, BATCH) with t[i]==y, in order, via
    // ballot + ffs. Mask is wave-uniform -> non-divergent processing loop.
    for (int base = b & ~63; base < BATCH; base += 64) {
        const int i = base + lane;
        unsigned long long mask = __ballot(i >= b && t[i] == y);
        while (mask) {
            const int i0 = base + (__ffsll((long long)mask) - 1);
            mask &= mask - 1;

            f4 x = reinterpret_cast<const f4*>(
                       inputs + (size_t)i0 * NUM_FEATURES)[lane];
            v.x = m * v.x + om * x.x;
            v.y = m * v.y + om * x.y;
            v.z = m * v.z + om * x.z;
            v.w = m * v.w + om * x.w;

            float s = v.x * v.x + v.y * v.y + v.z * v.z + v.w * v.w;
            #pragma unroll
            for (int off = 32; off > 0; off >>= 1)
                s += __shfl_xor(s, off);

            const float inv = 1.0f / fmaxf(sqrtf(s), 1e-12f);
            v.x *= inv; v.y *= inv; v.z *= inv; v.w *= inv;
        }
    }

    reinterpret_cast<f4*>(out + (size_t)y * NUM_FEATURES)[lane] = v;
}

extern "C" void kernel_launch(void* const* d_in, const int* in_sizes, int n_in,
                              void* d_out, int out_size, void* d_ws, size_t ws_size,
                              hipStream_t stream) {
    const float* inputs   = (const float*)d_in[0];
    const int*   targets  = (const int*)d_in[1];
    const float* features = (const float*)d_in[2];
    float*       out      = (float*)d_out;

    const long n4 = (long)NUM_SAMPLES * NUM_FEATURES / 4;  // 16.7M float4
    table_copy<<<COPY_BLOCKS, COPY_THREADS, 0, stream>>>(
        reinterpret_cast<const f4*>(features),
        reinterpret_cast<f4*>(out), n4);

    // Then overwrite the 1024 touched rows with the chained updates.
    memory_bank_update<<<BATCH, 64, 0, stream>>>(inputs, targets, features, out);
}